// Round 2
// baseline (1197.680 us; speedup 1.0000x reference)
//
#include <hip/hip_runtime.h>
#include <hip/hip_bf16.h>
#include <stdint.h>
#include <stddef.h>

typedef __hip_bfloat16 bf16;
typedef __attribute__((ext_vector_type(8))) short short8;
typedef __attribute__((ext_vector_type(4))) float f32x4;

#define EPI_NONE 0
#define EPI_SILU 1
#define EPI_RES  2
#define OUT_BF16  0
#define OUT_F32   1
#define OUT_SPLIT 2

__device__ __forceinline__ void gll16(const bf16* g, char* l) {
    __builtin_amdgcn_global_load_lds(
        (const __attribute__((address_space(1))) void*)g,
        (__attribute__((address_space(3))) void*)l, 16, 0, 0);
}

// ---------------------------------------------------------------------------
// m97-structure bf16 GEMM with optional bf16x3 split inputs:
//   C = (Ahi+Alo) @ (Bhi+Blo)^T  ~=  Ahi Bhi + Ahi Blo + Alo Bhi   (skip lo*lo)
// 128x128 tile, BK=64, 4 waves (2x2), 16x16x32 MFMA, global_load_lds staging.
// SPLIT: bit0 = A split, bit1 = B split. EPI: silu / +Res(f32). OUT: bf16/f32/split.
// ---------------------------------------------------------------------------
template<int SPLIT, int EPI, int OUT>
__global__ __launch_bounds__(256)
void gemm_bt(const bf16* __restrict__ Ahi, const bf16* __restrict__ Alo,
             const bf16* __restrict__ Bhi, const bf16* __restrict__ Blo,
             void* __restrict__ Cp, bf16* __restrict__ Clo,
             const float* __restrict__ Res,
             int M, int N, int K)
{
    constexpr bool SA = (SPLIT & 1) != 0;
    constexpr bool SB = (SPLIT & 2) != 0;

    const int t    = threadIdx.x;
    const int w    = t >> 6;
    const int lane = t & 63;
    const int wr   = w >> 1, wc = w & 1;
    const int lo   = lane & 15, hi = lane >> 4;
    const int brow = blockIdx.y * 128;
    const int bcol = blockIdx.x * 128;

    __shared__ bf16 AsH[128 * 64];
    __shared__ bf16 BsH[128 * 64];
    __shared__ bf16 AsL[SA ? 128 * 64 : 8];
    __shared__ bf16 BsL[SB ? 128 * 64 : 8];

    f32x4 acc[4][4];
#pragma unroll
    for (int m = 0; m < 4; ++m)
#pragma unroll
        for (int n = 0; n < 4; ++n)
            acc[m][n] = (f32x4){0.f, 0.f, 0.f, 0.f};

    const int r0 = t >> 3;          // 8 threads x 16B cover one 64-col row
    const int c0 = (t & 7) * 8;

    for (int k0 = 0; k0 < K; k0 += 64) {
#pragma unroll
        for (int i = 0; i < 4; ++i) {
            int r = i * 32 + r0;
            size_t aoff = (size_t)(brow + r) * K + (k0 + c0);
            size_t boff = (size_t)(bcol + r) * K + (k0 + c0);
            int ldst = i * 4096 + w * 1024;   // wave-uniform LDS byte base
            gll16(Ahi + aoff, (char*)AsH + ldst);
            gll16(Bhi + boff, (char*)BsH + ldst);
            if constexpr (SA) gll16(Alo + aoff, (char*)AsL + ldst);
            if constexpr (SB) gll16(Blo + boff, (char*)BsL + ldst);
        }
        __syncthreads();

#pragma unroll
        for (int kk = 0; kk < 64; kk += 32) {
            short8 aH[4], bH[4], aL[4], bL[4];
#pragma unroll
            for (int m = 0; m < 4; ++m) {
                int idx = (wr * 64 + m * 16 + lo) * 64 + kk + hi * 8;
                aH[m] = *(const short8*)&AsH[idx];
                if constexpr (SA) aL[m] = *(const short8*)&AsL[idx];
            }
#pragma unroll
            for (int n = 0; n < 4; ++n) {
                int idx = (wc * 64 + n * 16 + lo) * 64 + kk + hi * 8;
                bH[n] = *(const short8*)&BsH[idx];
                if constexpr (SB) bL[n] = *(const short8*)&BsL[idx];
            }
#pragma unroll
            for (int m = 0; m < 4; ++m)
#pragma unroll
                for (int n = 0; n < 4; ++n) {
                    acc[m][n] = __builtin_amdgcn_mfma_f32_16x16x32_bf16(
                        aH[m], bH[n], acc[m][n], 0, 0, 0);
                    if constexpr (SB)
                        acc[m][n] = __builtin_amdgcn_mfma_f32_16x16x32_bf16(
                            aH[m], bL[n], acc[m][n], 0, 0, 0);
                    if constexpr (SA)
                        acc[m][n] = __builtin_amdgcn_mfma_f32_16x16x32_bf16(
                            aL[m], bH[n], acc[m][n], 0, 0, 0);
                }
        }
        __syncthreads();
    }

#pragma unroll
    for (int m = 0; m < 4; ++m) {
#pragma unroll
        for (int n = 0; n < 4; ++n) {
#pragma unroll
            for (int j = 0; j < 4; ++j) {
                int row = brow + wr * 64 + m * 16 + hi * 4 + j;
                int col = bcol + wc * 64 + n * 16 + lo;
                size_t idx = (size_t)row * N + col;
                float v = acc[m][n][j];
                if (EPI == EPI_SILU) v = v / (1.f + __expf(-v));
                if (EPI == EPI_RES)  v += Res[idx];
                if (OUT == OUT_F32) {
                    ((float*)Cp)[idx] = v;
                } else if (OUT == OUT_BF16) {
                    ((bf16*)Cp)[idx] = __float2bfloat16(v);
                } else {
                    bf16 vh = __float2bfloat16(v);
                    ((bf16*)Cp)[idx] = vh;
                    Clo[idx] = __float2bfloat16(v - __bfloat162float(vh));
                }
            }
        }
    }
}

// ---- split x fp32 -> (hi, lo) bf16 pair, vectorized ----
__global__ void split_x_kernel(const float* __restrict__ x,
                               bf16* __restrict__ xh, bf16* __restrict__ xl)
{
    size_t i = ((size_t)blockIdx.x * 256 + threadIdx.x) * 4;
    float4 v = *(const float4*)(x + i);
    ushort4 oh, ol;
    float vv[4] = {v.x, v.y, v.z, v.w};
    unsigned short rh[4], rl[4];
#pragma unroll
    for (int j = 0; j < 4; ++j) {
        bf16 h_ = __float2bfloat16(vv[j]);
        bf16 l_ = __float2bfloat16(vv[j] - __bfloat162float(h_));
        rh[j] = *(unsigned short*)&h_;
        rl[j] = *(unsigned short*)&l_;
    }
    oh.x = rh[0]; oh.y = rh[1]; oh.z = rh[2]; oh.w = rh[3];
    ol.x = rl[0]; ol.y = rl[1]; ol.z = rl[2]; ol.w = rl[3];
    *(ushort4*)(xh + i) = oh;
    *(ushort4*)(xl + i) = ol;
}

// ---- transpose + split one 512x512 weight: WT[n][k] = W[k][n] ----
__global__ void transw_kernel(const float* __restrict__ W,
                              bf16* __restrict__ WTh, bf16* __restrict__ WTl)
{
    __shared__ float tile[32][33];
    int bx = blockIdx.x * 32, by = blockIdx.y * 32;
    int tx = threadIdx.x, ty = threadIdx.y;      // (32, 8)
#pragma unroll
    for (int i = 0; i < 32; i += 8)
        tile[ty + i][tx] = W[(size_t)(by + ty + i) * 512 + bx + tx];
    __syncthreads();
#pragma unroll
    for (int i = 0; i < 32; i += 8) {
        float v = tile[tx][ty + i];
        bf16 h_ = __float2bfloat16(v);
        size_t idx = (size_t)(bx + ty + i) * 512 + by + tx;
        WTh[idx] = h_;
        WTl[idx] = __float2bfloat16(v - __bfloat162float(h_));
    }
}

// ---- per-column (over q) online max/sumexp partials on S[4096,4096] ----
__global__ void colstats_part_kernel(const float* __restrict__ S,
                                     float* __restrict__ mp, float* __restrict__ zp)
{
    int col = blockIdx.x * 256 + threadIdx.x;
    int r0  = blockIdx.y * 256;
    float m = -1e30f, z = 0.f;
    for (int r = 0; r < 256; ++r) {
        float s  = S[(size_t)(r0 + r) * 4096 + col];
        float nm = fmaxf(m, s);
        z = z * __expf(m - nm) + __expf(s - nm);
        m = nm;
    }
    mp[blockIdx.y * 4096 + col] = m;
    zp[blockIdx.y * 4096 + col] = z;
}

__global__ void colstats_comb_kernel(const float* __restrict__ mp, const float* __restrict__ zp,
                                     float* __restrict__ mcol, float* __restrict__ rinv)
{
    int col = blockIdx.x * 256 + threadIdx.x;
    float m = -1e30f;
#pragma unroll
    for (int i = 0; i < 16; ++i) m = fmaxf(m, mp[i * 4096 + col]);
    float z = 0.f;
#pragma unroll
    for (int i = 0; i < 16; ++i) z += zp[i * 4096 + col] * __expf(mp[i * 4096 + col] - m);
    mcol[col] = m;
    rinv[col] = 1.f / z;
}

// ---- P[q,k] = bf16(exp(S[q,k] - mcol[k])) ----
__global__ void exp_p_kernel(const float* __restrict__ S, const float* __restrict__ mcol,
                             bf16* __restrict__ P)
{
    size_t i = ((size_t)blockIdx.x * 256 + threadIdx.x) * 4;
    int k = (int)(i & 4095);
    float4 s  = *(const float4*)(S + i);
    float4 mc = *(const float4*)(mcol + k);
    bf16 b0 = __float2bfloat16(__expf(s.x - mc.x));
    bf16 b1 = __float2bfloat16(__expf(s.y - mc.y));
    bf16 b2 = __float2bfloat16(__expf(s.z - mc.z));
    bf16 b3 = __float2bfloat16(__expf(s.w - mc.w));
    ushort4 o;
    o.x = *(unsigned short*)&b0; o.y = *(unsigned short*)&b1;
    o.z = *(unsigned short*)&b2; o.w = *(unsigned short*)&b3;
    *(ushort4*)(P + i) = o;
}

// ---- VT[d][k] = split( V[k][d] * rinv[k] )  (per batch) ----
__global__ void transv_kernel(const bf16* __restrict__ V, const float* __restrict__ rinv,
                              bf16* __restrict__ VTh, bf16* __restrict__ VTl)
{
    __shared__ float tile[32][33];
    int bk = blockIdx.x * 32, bd = blockIdx.y * 32;
    int tx = threadIdx.x, ty = threadIdx.y;      // (32, 8)
#pragma unroll
    for (int i = 0; i < 32; i += 8) {
        int k = bk + ty + i;
        tile[ty + i][tx] = __bfloat162float(V[(size_t)k * 512 + bd + tx]) * rinv[k];
    }
    __syncthreads();
#pragma unroll
    for (int i = 0; i < 32; i += 8) {
        float v = tile[tx][ty + i];
        bf16 h_ = __float2bfloat16(v);
        size_t idx = (size_t)(bd + ty + i) * 4096 + bk + tx;
        VTh[idx] = h_;
        VTl[idx] = __float2bfloat16(v - __bfloat162float(h_));
    }
}

// ---------------------------------------------------------------------------
extern "C" void kernel_launch(void* const* d_in, const int* in_sizes, int n_in,
                              void* d_out, int out_size, void* d_ws, size_t ws_size,
                              hipStream_t stream)
{
    const int B = 4, N = 4096, D = 512;
    const size_t MALL = (size_t)B * N;          // 16384
    const size_t ND = MALL * D;                 // 8.4M elems
    const float* x = (const float*)d_in[0];
    const float* Wf[10];
    for (int i = 0; i < 10; ++i) Wf[i] = (const float*)d_in[1 + i];
    // Wf: 0 qW1, 1 qW2, 2 kW1, 3 kW2, 4 vW1, 5 vW2, 6 aWq, 7 aWk, 8 aWv, 9 Wout

    char* ws = (char*)d_ws;
    size_t off = 0;
    auto carve = [&](size_t bytes) -> char* {
        char* p = ws + off;
        off = (off + bytes + 255) & ~(size_t)255;
        return p;
    };

    bf16* xh = (bf16*)carve(2 * ND * 2);   bf16* xl = xh + ND;        // 33.6 MB
    bf16 *wH[10], *wL[10];
    for (int i = 0; i < 10; ++i) {                                    // 10 MB
        wH[i] = (bf16*)carve(2 * (size_t)D * D * 2);
        wL[i] = wH[i] + (size_t)D * D;
    }
    bf16* t1h = (bf16*)carve(2 * ND * 2);  bf16* t1l = t1h + ND;      // 33.6 MB
    bf16* hh  = (bf16*)carve(2 * ND * 2);  bf16* hl  = hh + ND;       // 33.6 MB
    bf16* Qh  = (bf16*)carve(2 * ND * 2);  bf16* Ql  = Qh + ND;       // 33.6 MB
    bf16* Kh  = (bf16*)carve(2 * ND * 2);  bf16* Kl  = Kh + ND;       // 33.6 MB
    bf16* V   = (bf16*)carve(ND * 2);                                 // 16.8 MB
    float* S  = (float*)carve((size_t)N * N * 4);                     // 67 MB
    float* mp   = (float*)carve(16 * 4096 * 4);
    float* zp   = (float*)carve(16 * 4096 * 4);
    float* mcol = (float*)carve(4096 * 4);
    float* rinv = (float*)carve(4096 * 4);
    // reuse dead buffers after the branch phase:
    bf16* P   = (bf16*)d_out;              // N*N bf16 == out_size f32 bytes
    bf16* VTh = t1h;                       // D*N split pair in t1 buffer
    bf16* VTl = t1h + (size_t)D * N;
    bf16* O   = hh;                        // MALL*D bf16 in h buffer
    (void)ws_size; (void)in_sizes; (void)n_in; (void)out_size;

    // ---- splits / transposes ----
    split_x_kernel<<<dim3((unsigned)(ND / 1024)), 256, 0, stream>>>(x, xh, xl);
    for (int i = 0; i < 10; ++i)
        transw_kernel<<<dim3(16, 16), dim3(32, 8), 0, stream>>>(Wf[i], wH[i], wL[i]);

    // ---- three ResiMLP branches (bf16x3 chain; Q,K split out, V plain) ----
    dim3 gB(D / 128, (unsigned)(MALL / 128));
    const int W1i[3] = {0, 2, 4}, W2i[3] = {1, 3, 5}, aWi[3] = {6, 7, 8};
    for (int br = 0; br < 3; ++br) {
        gemm_bt<3, EPI_SILU, OUT_SPLIT><<<gB, 256, 0, stream>>>(
            xh, xl, wH[W1i[br]], wL[W1i[br]], t1h, t1l, nullptr, (int)MALL, D, D);
        gemm_bt<3, EPI_RES, OUT_SPLIT><<<gB, 256, 0, stream>>>(
            t1h, t1l, wH[W2i[br]], wL[W2i[br]], hh, hl, x, (int)MALL, D, D);
        if (br == 0)
            gemm_bt<3, EPI_NONE, OUT_SPLIT><<<gB, 256, 0, stream>>>(
                hh, hl, wH[aWi[br]], wL[aWi[br]], Qh, Ql, nullptr, (int)MALL, D, D);
        else if (br == 1)
            gemm_bt<3, EPI_NONE, OUT_SPLIT><<<gB, 256, 0, stream>>>(
                hh, hl, wH[aWi[br]], wL[aWi[br]], Kh, Kl, nullptr, (int)MALL, D, D);
        else
            gemm_bt<3, EPI_NONE, OUT_BF16><<<gB, 256, 0, stream>>>(
                hh, hl, wH[aWi[br]], wL[aWi[br]], V, nullptr, nullptr, (int)MALL, D, D);
    }

    // ---- attention per batch: S = QK^T (split); column softmax; P; V'; PV ----
    for (int b = 0; b < B; ++b) {
        size_t boff = (size_t)b * N * D;
        gemm_bt<3, EPI_NONE, OUT_F32><<<dim3(N / 128, N / 128), 256, 0, stream>>>(
            Qh + boff, Ql + boff, Kh + boff, Kl + boff, S, nullptr, nullptr, N, N, D);
        colstats_part_kernel<<<dim3(16, 16), 256, 0, stream>>>(S, mp, zp);
        colstats_comb_kernel<<<16, 256, 0, stream>>>(mp, zp, mcol, rinv);
        exp_p_kernel<<<(unsigned)((size_t)N * N / 1024), 256, 0, stream>>>(S, mcol, P);
        transv_kernel<<<dim3(N / 32, D / 32), dim3(32, 8), 0, stream>>>(
            V + boff, rinv, VTh, VTl);
        gemm_bt<2, EPI_NONE, OUT_BF16><<<dim3(D / 128, N / 128), 256, 0, stream>>>(
            P, nullptr, VTh, VTl, O + boff, nullptr, nullptr, N, D, N);
    }

    // ---- final projection: d_out = O @ (WoutHi + WoutLo)  (overwrites P) ----
    gemm_bt<2, EPI_NONE, OUT_F32><<<gB, 256, 0, stream>>>(
        O, nullptr, wH[9], wL[9], d_out, nullptr, nullptr, (int)MALL, D, D);
}

// Round 3
// 1023.760 us; speedup vs baseline: 1.1699x; 1.1699x over previous
//
#include <hip/hip_runtime.h>
#include <hip/hip_bf16.h>
#include <stdint.h>
#include <stddef.h>

typedef __hip_bfloat16 bf16;
typedef __attribute__((ext_vector_type(8))) short short8;
typedef __attribute__((ext_vector_type(4))) float f32x4;

#define EPI_NONE 0
#define EPI_SILU 1
#define EPI_RES  2
#define OUT_BF16  0
#define OUT_F32   1
#define OUT_SPLIT 2

__device__ __forceinline__ void gll16(const bf16* g, char* l) {
    __builtin_amdgcn_global_load_lds(
        (const __attribute__((address_space(1))) void*)g,
        (__attribute__((address_space(3))) void*)l, 16, 0, 0);
}

// ---------------------------------------------------------------------------
// m97-structure bf16 GEMM, optional bf16x3 split inputs, optional z-batching.
//   C = (Ahi+Alo) @ (Bhi+Blo)^T ~= AhiBhi + AhiBlo + AloBhi   (lo*lo skipped)
// 128x128 tile, BK=64, 4 waves (2x2), 16x16x32 MFMA, global_load_lds staging.
// LDS tiles XOR-swizzled: LDS(r, chunk c) holds global (r, c ^ (r&7)); the
// source permutation stays within one 128B row segment (coalescing intact),
// the read applies the same XOR (involution). Kills the 16-way ds_read_b128
// bank conflict of the 128B-stride row-major tile.
// SPLIT: bit0 = A split, bit1 = B split. Strides sA/sB/sC in elements (z dim).
// ---------------------------------------------------------------------------
template<int SPLIT, int EPI, int OUT>
__global__ __launch_bounds__(256)
void gemm_bt(const bf16* __restrict__ Ahi, const bf16* __restrict__ Alo,
             const bf16* __restrict__ Bhi, const bf16* __restrict__ Blo,
             void* __restrict__ Cp, bf16* __restrict__ Clo,
             const float* __restrict__ Res,
             int M, int N, int K,
             unsigned long long sA, unsigned long long sB, unsigned long long sC)
{
    constexpr bool SA = (SPLIT & 1) != 0;
    constexpr bool SB = (SPLIT & 2) != 0;

    const size_t zA = (size_t)blockIdx.z * sA;
    const size_t zB = (size_t)blockIdx.z * sB;
    const size_t zC = (size_t)blockIdx.z * sC;
    Ahi += zA; Bhi += zB;
    if constexpr (SA) Alo += zA;
    if constexpr (SB) Blo += zB;

    const int t    = threadIdx.x;
    const int w    = t >> 6;
    const int lane = t & 63;
    const int wr   = w >> 1, wc = w & 1;
    const int lo   = lane & 15, hi = lane >> 4;
    const int brow = blockIdx.y * 128;
    const int bcol = blockIdx.x * 128;

    __shared__ bf16 AsH[128 * 64];
    __shared__ bf16 BsH[128 * 64];
    __shared__ bf16 AsL[SA ? 128 * 64 : 8];
    __shared__ bf16 BsL[SB ? 128 * 64 : 8];

    f32x4 acc[4][4];
#pragma unroll
    for (int m = 0; m < 4; ++m)
#pragma unroll
        for (int n = 0; n < 4; ++n)
            acc[m][n] = (f32x4){0.f, 0.f, 0.f, 0.f};

    const int r0 = t >> 3;                         // row within 32-row stripe
    // swizzled source chunk: thread covers LDS slot (r, t&7); its content is
    // global chunk (t&7) ^ (r&7); r&7 == (t>>3)&7 for every stripe i.
    const int cswz = ((t & 7) ^ ((t >> 3) & 7)) * 8;
    const int rA7  = lo & 7;                       // read-side row parity

    for (int k0 = 0; k0 < K; k0 += 64) {
#pragma unroll
        for (int i = 0; i < 4; ++i) {
            int r = i * 32 + r0;
            size_t aoff = (size_t)(brow + r) * K + (k0 + cswz);
            size_t boff = (size_t)(bcol + r) * K + (k0 + cswz);
            int ldst = i * 4096 + w * 1024;        // wave-uniform LDS byte base
            gll16(Ahi + aoff, (char*)AsH + ldst);
            gll16(Bhi + boff, (char*)BsH + ldst);
            if constexpr (SA) gll16(Alo + aoff, (char*)AsL + ldst);
            if constexpr (SB) gll16(Blo + boff, (char*)BsL + ldst);
        }
        __syncthreads();

#pragma unroll
        for (int kk = 0; kk < 64; kk += 32) {
            short8 aH[4], bH[4], aL[4], bL[4];
#pragma unroll
            for (int m = 0; m < 4; ++m) {
                int idx = (wr * 64 + m * 16 + lo) * 64 +
                          ((((kk >> 3) + hi) ^ rA7) * 8);
                aH[m] = *(const short8*)&AsH[idx];
                if constexpr (SA) aL[m] = *(const short8*)&AsL[idx];
            }
#pragma unroll
            for (int n = 0; n < 4; ++n) {
                int idx = (wc * 64 + n * 16 + lo) * 64 +
                          ((((kk >> 3) + hi) ^ rA7) * 8);
                bH[n] = *(const short8*)&BsH[idx];
                if constexpr (SB) bL[n] = *(const short8*)&BsL[idx];
            }
#pragma unroll
            for (int m = 0; m < 4; ++m)
#pragma unroll
                for (int n = 0; n < 4; ++n) {
                    acc[m][n] = __builtin_amdgcn_mfma_f32_16x16x32_bf16(
                        aH[m], bH[n], acc[m][n], 0, 0, 0);
                    if constexpr (SB)
                        acc[m][n] = __builtin_amdgcn_mfma_f32_16x16x32_bf16(
                            aH[m], bL[n], acc[m][n], 0, 0, 0);
                    if constexpr (SA)
                        acc[m][n] = __builtin_amdgcn_mfma_f32_16x16x32_bf16(
                            aL[m], bH[n], acc[m][n], 0, 0, 0);
                }
        }
        __syncthreads();
    }

#pragma unroll
    for (int m = 0; m < 4; ++m) {
#pragma unroll
        for (int n = 0; n < 4; ++n) {
#pragma unroll
            for (int j = 0; j < 4; ++j) {
                int row = brow + wr * 64 + m * 16 + hi * 4 + j;
                int col = bcol + wc * 64 + n * 16 + lo;
                size_t idx = (size_t)row * N + col + zC;
                float v = acc[m][n][j];
                if (EPI == EPI_SILU) v = v / (1.f + __expf(-v));
                if (EPI == EPI_RES)  v += Res[idx];
                if (OUT == OUT_F32) {
                    ((float*)Cp)[idx] = v;
                } else if (OUT == OUT_BF16) {
                    ((bf16*)Cp)[idx] = __float2bfloat16(v);
                } else {
                    bf16 vh = __float2bfloat16(v);
                    ((bf16*)Cp)[idx] = vh;
                    Clo[idx] = __float2bfloat16(v - __bfloat162float(vh));
                }
            }
        }
    }
}

// ---- split x fp32 -> (hi, lo) bf16 pair, vectorized ----
__global__ void split_x_kernel(const float* __restrict__ x,
                               bf16* __restrict__ xh, bf16* __restrict__ xl)
{
    size_t i = ((size_t)blockIdx.x * 256 + threadIdx.x) * 4;
    float4 v = *(const float4*)(x + i);
    float vv[4] = {v.x, v.y, v.z, v.w};
    unsigned short rh[4], rl[4];
#pragma unroll
    for (int j = 0; j < 4; ++j) {
        bf16 h_ = __float2bfloat16(vv[j]);
        bf16 l_ = __float2bfloat16(vv[j] - __bfloat162float(h_));
        rh[j] = *(unsigned short*)&h_;
        rl[j] = *(unsigned short*)&l_;
    }
    ushort4 oh = {rh[0], rh[1], rh[2], rh[3]};
    ushort4 ol = {rl[0], rl[1], rl[2], rl[3]};
    *(ushort4*)(xh + i) = oh;
    *(ushort4*)(xl + i) = ol;
}

// ---- transpose + split one 512x512 weight: WT[n][k] = W[k][n] ----
__global__ void transw_kernel(const float* __restrict__ W,
                              bf16* __restrict__ WTh, bf16* __restrict__ WTl)
{
    __shared__ float tile[32][33];
    int bx = blockIdx.x * 32, by = blockIdx.y * 32;
    int tx = threadIdx.x, ty = threadIdx.y;      // (32, 8)
#pragma unroll
    for (int i = 0; i < 32; i += 8)
        tile[ty + i][tx] = W[(size_t)(by + ty + i) * 512 + bx + tx];
    __syncthreads();
#pragma unroll
    for (int i = 0; i < 32; i += 8) {
        float v = tile[tx][ty + i];
        bf16 h_ = __float2bfloat16(v);
        size_t idx = (size_t)(bx + ty + i) * 512 + by + tx;
        WTh[idx] = h_;
        WTl[idx] = __float2bfloat16(v - __bfloat162float(h_));
    }
}

// ---- per-column (over q) online max/sumexp partials on S[4096,4096] ----
__global__ void colstats_part_kernel(const float* __restrict__ S,
                                     float* __restrict__ mp, float* __restrict__ zp)
{
    int col = blockIdx.x * 256 + threadIdx.x;
    int r0  = blockIdx.y * 256;
    float m = -1e30f, z = 0.f;
    for (int r = 0; r < 256; ++r) {
        float s  = S[(size_t)(r0 + r) * 4096 + col];
        float nm = fmaxf(m, s);
        z = z * __expf(m - nm) + __expf(s - nm);
        m = nm;
    }
    mp[blockIdx.y * 4096 + col] = m;
    zp[blockIdx.y * 4096 + col] = z;
}

__global__ void colstats_comb_kernel(const float* __restrict__ mp, const float* __restrict__ zp,
                                     float* __restrict__ mcol, float* __restrict__ rinv)
{
    int col = blockIdx.x * 256 + threadIdx.x;
    float m = -1e30f;
#pragma unroll
    for (int i = 0; i < 16; ++i) m = fmaxf(m, mp[i * 4096 + col]);
    float z = 0.f;
#pragma unroll
    for (int i = 0; i < 16; ++i) z += zp[i * 4096 + col] * __expf(mp[i * 4096 + col] - m);
    mcol[col] = m;
    rinv[col] = 1.f / z;
}

// ---- P[q,k] = bf16( exp(S[q,k] - mcol[k]) * rinv[k] )  (1/Z folded in) ----
__global__ void exp_p_kernel(const float* __restrict__ S, const float* __restrict__ mcol,
                             const float* __restrict__ rinv, bf16* __restrict__ P)
{
    size_t i = ((size_t)blockIdx.x * 256 + threadIdx.x) * 4;
    int k = (int)(i & 4095);
    float4 s  = *(const float4*)(S + i);
    float4 mc = *(const float4*)(mcol + k);
    float4 rv = *(const float4*)(rinv + k);
    bf16 b0 = __float2bfloat16(__expf(s.x - mc.x) * rv.x);
    bf16 b1 = __float2bfloat16(__expf(s.y - mc.y) * rv.y);
    bf16 b2 = __float2bfloat16(__expf(s.z - mc.z) * rv.z);
    bf16 b3 = __float2bfloat16(__expf(s.w - mc.w) * rv.w);
    ushort4 o;
    o.x = *(unsigned short*)&b0; o.y = *(unsigned short*)&b1;
    o.z = *(unsigned short*)&b2; o.w = *(unsigned short*)&b3;
    *(ushort4*)(P + i) = o;
}

// ---- VT[b][d][k] = V[b][k][d]  (plain bf16 transpose, all batches) ----
__global__ void transv_kernel(const bf16* __restrict__ V, bf16* __restrict__ VT)
{
    __shared__ float tile[32][33];
    const size_t N = 4096, D = 512;
    size_t b = blockIdx.z;
    int bk = blockIdx.x * 32, bd = blockIdx.y * 32;
    int tx = threadIdx.x, ty = threadIdx.y;      // (32, 8)
#pragma unroll
    for (int i = 0; i < 32; i += 8)
        tile[ty + i][tx] = __bfloat162float(V[b * N * D + (size_t)(bk + ty + i) * D + bd + tx]);
    __syncthreads();
#pragma unroll
    for (int i = 0; i < 32; i += 8)
        VT[b * D * N + (size_t)(bd + ty + i) * N + bk + tx] =
            __float2bfloat16(tile[tx][ty + i]);
}

// ---------------------------------------------------------------------------
extern "C" void kernel_launch(void* const* d_in, const int* in_sizes, int n_in,
                              void* d_out, int out_size, void* d_ws, size_t ws_size,
                              hipStream_t stream)
{
    const int B = 4, N = 4096, D = 512;
    const size_t MALL = (size_t)B * N;          // 16384
    const size_t ND = MALL * D;                 // 8.4M elems
    const float* x = (const float*)d_in[0];
    const float* Wf[10];
    for (int i = 0; i < 10; ++i) Wf[i] = (const float*)d_in[1 + i];
    // Wf: 0 qW1, 1 qW2, 2 kW1, 3 kW2, 4 vW1, 5 vW2, 6 aWq, 7 aWk, 8 aWv, 9 Wout

    char* ws = (char*)d_ws;
    size_t off = 0;
    auto carve = [&](size_t bytes) -> char* {
        char* p = ws + off;
        off = (off + bytes + 255) & ~(size_t)255;
        return p;
    };

    // NOTE: xh, t1h, hh, Qh regions are carved CONSECUTIVELY and each is
    // exactly N*N*2 bytes, so after they die they form a uniformly strided
    // P_all[4] for the z-batched PV GEMM.
    const size_t PBYTES = (size_t)N * N * 2;     // 33,554,432
    bf16* xh = (bf16*)carve(PBYTES);       bf16* xl = xh + ND;
    bf16* t1h = (bf16*)carve(PBYTES);      bf16* t1l = t1h + ND;
    bf16* hh  = (bf16*)carve(PBYTES);      bf16* hl  = hh + ND;
    bf16* Qh  = (bf16*)carve(PBYTES);      bf16* Ql  = Qh + ND;
    bf16* Kh  = (bf16*)carve(PBYTES);      bf16* Kl  = Kh + ND;
    bf16* V   = (bf16*)carve(ND * 2);
    bf16 *wH[10], *wL[10];
    for (int i = 0; i < 10; ++i) {
        wH[i] = (bf16*)carve(2 * (size_t)D * D * 2);
        wL[i] = wH[i] + (size_t)D * D;
    }
    bf16* VT = (bf16*)carve((size_t)B * D * N * 2);
    float* mp   = (float*)carve(16 * 4096 * 4);
    float* zp   = (float*)carve(16 * 4096 * 4);
    float* mcol = (float*)carve(4096 * 4);
    float* rinv = (float*)carve(4096 * 4);
    size_t offNoS = off;
    float* S = (float*)carve((size_t)N * N * 4);
    bool roomy = (ws_size >= off);
    if (!roomy) S = (float*)xh;             // fallback: S in dead x+t1 region
    bf16* O = Kh;                            // dead after last QK^T (16.8MB of 33.6)
    (void)offNoS; (void)in_sizes; (void)n_in; (void)out_size;

    // ---- splits / transposes ----
    split_x_kernel<<<dim3((unsigned)(ND / 1024)), 256, 0, stream>>>(x, xh, xl);
    for (int i = 0; i < 10; ++i)
        transw_kernel<<<dim3(16, 16), dim3(32, 8), 0, stream>>>(Wf[i], wH[i], wL[i]);

    // ---- three ResiMLP branches (bf16x3 chain; Q,K split out, V plain) ----
    dim3 gB(D / 128, (unsigned)(MALL / 128));
    const int W1i[3] = {0, 2, 4}, W2i[3] = {1, 3, 5}, aWi[3] = {6, 7, 8};
    for (int br = 0; br < 3; ++br) {
        gemm_bt<3, EPI_SILU, OUT_SPLIT><<<gB, 256, 0, stream>>>(
            xh, xl, wH[W1i[br]], wL[W1i[br]], t1h, t1l, nullptr,
            (int)MALL, D, D, 0, 0, 0);
        gemm_bt<3, EPI_RES, OUT_SPLIT><<<gB, 256, 0, stream>>>(
            t1h, t1l, wH[W2i[br]], wL[W2i[br]], hh, hl, x,
            (int)MALL, D, D, 0, 0, 0);
        if (br == 0)
            gemm_bt<3, EPI_NONE, OUT_SPLIT><<<gB, 256, 0, stream>>>(
                hh, hl, wH[6], wL[6], Qh, Ql, nullptr, (int)MALL, D, D, 0, 0, 0);
        else if (br == 1)
            gemm_bt<3, EPI_NONE, OUT_SPLIT><<<gB, 256, 0, stream>>>(
                hh, hl, wH[7], wL[7], Kh, Kl, nullptr, (int)MALL, D, D, 0, 0, 0);
        else
            gemm_bt<3, EPI_NONE, OUT_BF16><<<gB, 256, 0, stream>>>(
                hh, hl, wH[8], wL[8], V, nullptr, nullptr, (int)MALL, D, D, 0, 0, 0);
    }

    // ---- V transpose for all batches (unscaled; 1/Z folded into P) ----
    transv_kernel<<<dim3(N / 32, D / 32, B), dim3(32, 8), 0, stream>>>(V, VT);

    // ---- per batch: S = QK^T (split); column stats; P = A (prescaled) ----
    bf16* P_all = xh;                        // x/t1/h/Q regions, stride N*N
    for (int b = 0; b < B; ++b) {
        size_t boff = (size_t)b * N * D;
        gemm_bt<3, EPI_NONE, OUT_F32><<<dim3(N / 128, N / 128), 256, 0, stream>>>(
            Qh + boff, Ql + boff, Kh + boff, Kl + boff, S, nullptr, nullptr,
            N, N, D, 0, 0, 0);
        colstats_part_kernel<<<dim3(16, 16), 256, 0, stream>>>(S, mp, zp);
        colstats_comb_kernel<<<16, 256, 0, stream>>>(mp, zp, mcol, rinv);
        bf16* Pb = roomy ? (P_all + (size_t)b * N * N) : (bf16*)d_out;
        exp_p_kernel<<<(unsigned)((size_t)N * N / 1024), 256, 0, stream>>>(
            S, mcol, rinv, Pb);
        if (!roomy) {
            gemm_bt<0, EPI_NONE, OUT_BF16><<<dim3(D / 128, N / 128), 256, 0, stream>>>(
                Pb, nullptr, VT + (size_t)b * D * N, nullptr, O + boff,
                nullptr, nullptr, N, D, N, 0, 0, 0);
        }
    }

    // ---- z-batched PV: O[b] = P[b] @ VT[b]^T, grid 512 blocks ----
    if (roomy) {
        gemm_bt<0, EPI_NONE, OUT_BF16><<<dim3(D / 128, N / 128, B), 256, 0, stream>>>(
            P_all, nullptr, VT, nullptr, O, nullptr, nullptr,
            N, D, N, (unsigned long long)N * N, (unsigned long long)D * N,
            (unsigned long long)N * D);
    }

    // ---- final projection: d_out = O @ (WoutHi + WoutLo) ----
    gemm_bt<2, EPI_NONE, OUT_F32><<<gB, 256, 0, stream>>>(
        O, nullptr, wH[9], wL[9], d_out, nullptr, nullptr,
        (int)MALL, D, D, 0, 0, 0);
}

// Round 4
// 827.854 us; speedup vs baseline: 1.4467x; 1.2366x over previous
//
#include <hip/hip_runtime.h>
#include <hip/hip_bf16.h>
#include <stdint.h>
#include <stddef.h>

typedef __hip_bfloat16 bf16;
typedef __attribute__((ext_vector_type(8))) short short8;
typedef __attribute__((ext_vector_type(4))) float f32x4;

#define EPI_NONE 0
#define EPI_SILU 1
#define EPI_RES  2
#define OUT_BF16  0
#define OUT_F32   1
#define OUT_SPLIT 2
#define OUT_VT    3   // write C transposed into VT[b][d][token], token = row

__device__ __forceinline__ void gll16(const bf16* g, char* l) {
    __builtin_amdgcn_global_load_lds(
        (const __attribute__((address_space(1))) void*)g,
        (__attribute__((address_space(3))) void*)l, 16, 0, 0);
}

// ---------------------------------------------------------------------------
// m97-structure bf16 GEMM, optional bf16x3 split inputs, optional z-batching.
//   C = (Ahi+Alo) @ (Bhi+Blo)^T ~= AhiBhi + AhiBlo + AloBhi   (lo*lo skipped)
// 128x128 tile, BK=64, 4 waves (2x2), 16x16x32 MFMA, global_load_lds staging.
// LDS XOR-swizzle (r&7 on 16B chunks): linear LDS dest + inverse-permuted
// global source + same-XOR read => 0 bank conflicts (verified round 3).
// ---------------------------------------------------------------------------
template<int SPLIT, int EPI, int OUT>
__global__ __launch_bounds__(256)
void gemm_bt(const bf16* __restrict__ Ahi, const bf16* __restrict__ Alo,
             const bf16* __restrict__ Bhi, const bf16* __restrict__ Blo,
             void* __restrict__ Cp, bf16* __restrict__ Clo,
             const float* __restrict__ Res,
             int M, int N, int K,
             unsigned long long sA, unsigned long long sB, unsigned long long sC)
{
    constexpr bool SA = (SPLIT & 1) != 0;
    constexpr bool SB = (SPLIT & 2) != 0;

    const size_t zA = (size_t)blockIdx.z * sA;
    const size_t zB = (size_t)blockIdx.z * sB;
    const size_t zC = (size_t)blockIdx.z * sC;
    Ahi += zA; Bhi += zB;
    if constexpr (SA) Alo += zA;
    if constexpr (SB) Blo += zB;

    const int t    = threadIdx.x;
    const int w    = t >> 6;
    const int lane = t & 63;
    const int wr   = w >> 1, wc = w & 1;
    const int lo   = lane & 15, hi = lane >> 4;
    const int brow = blockIdx.y * 128;
    const int bcol = blockIdx.x * 128;

    __shared__ bf16 AsH[128 * 64];
    __shared__ bf16 BsH[128 * 64];
    __shared__ bf16 AsL[SA ? 128 * 64 : 8];
    __shared__ bf16 BsL[SB ? 128 * 64 : 8];

    f32x4 acc[4][4];
#pragma unroll
    for (int m = 0; m < 4; ++m)
#pragma unroll
        for (int n = 0; n < 4; ++n)
            acc[m][n] = (f32x4){0.f, 0.f, 0.f, 0.f};

    const int r0 = t >> 3;                         // row within 32-row stripe
    const int cswz = ((t & 7) ^ ((t >> 3) & 7)) * 8;   // inverse-swizzled src chunk
    const int rA7  = lo & 7;                       // read-side row parity

    for (int k0 = 0; k0 < K; k0 += 64) {
#pragma unroll
        for (int i = 0; i < 4; ++i) {
            int r = i * 32 + r0;
            size_t aoff = (size_t)(brow + r) * K + (k0 + cswz);
            size_t boff = (size_t)(bcol + r) * K + (k0 + cswz);
            int ldst = i * 4096 + w * 1024;        // wave-uniform LDS byte base
            gll16(Ahi + aoff, (char*)AsH + ldst);
            gll16(Bhi + boff, (char*)BsH + ldst);
            if constexpr (SA) gll16(Alo + aoff, (char*)AsL + ldst);
            if constexpr (SB) gll16(Blo + boff, (char*)BsL + ldst);
        }
        __syncthreads();

#pragma unroll
        for (int kk = 0; kk < 64; kk += 32) {
            short8 aH[4], bH[4], aL[4], bL[4];
#pragma unroll
            for (int m = 0; m < 4; ++m) {
                int idx = (wr * 64 + m * 16 + lo) * 64 +
                          ((((kk >> 3) + hi) ^ rA7) * 8);
                aH[m] = *(const short8*)&AsH[idx];
                if constexpr (SA) aL[m] = *(const short8*)&AsL[idx];
            }
#pragma unroll
            for (int n = 0; n < 4; ++n) {
                int idx = (wc * 64 + n * 16 + lo) * 64 +
                          ((((kk >> 3) + hi) ^ rA7) * 8);
                bH[n] = *(const short8*)&BsH[idx];
                if constexpr (SB) bL[n] = *(const short8*)&BsL[idx];
            }
#pragma unroll
            for (int m = 0; m < 4; ++m)
#pragma unroll
                for (int n = 0; n < 4; ++n) {
                    acc[m][n] = __builtin_amdgcn_mfma_f32_16x16x32_bf16(
                        aH[m], bH[n], acc[m][n], 0, 0, 0);
                    if constexpr (SB)
                        acc[m][n] = __builtin_amdgcn_mfma_f32_16x16x32_bf16(
                            aH[m], bL[n], acc[m][n], 0, 0, 0);
                    if constexpr (SA)
                        acc[m][n] = __builtin_amdgcn_mfma_f32_16x16x32_bf16(
                            aL[m], bH[n], acc[m][n], 0, 0, 0);
                }
        }
        __syncthreads();
    }

#pragma unroll
    for (int m = 0; m < 4; ++m) {
#pragma unroll
        for (int n = 0; n < 4; ++n) {
            if constexpr (OUT == OUT_VT) {
                // VT[b][d][token]: 4 consecutive tokens (j) per lane -> 8B store
                int row0 = brow + wr * 64 + m * 16 + hi * 4;
                int col  = bcol + wc * 64 + n * 16 + lo;      // d index
                int bb = row0 >> 12, n0 = row0 & 4095;
                unsigned short u[4];
#pragma unroll
                for (int j = 0; j < 4; ++j) {
                    bf16 vb = __float2bfloat16(acc[m][n][j]);
                    u[j] = *(unsigned short*)&vb;
                }
                ushort4 pack = {u[0], u[1], u[2], u[3]};
                *(ushort4*)&((bf16*)Cp)[((size_t)(bb * 512 + col) << 12) + n0] = pack;
            } else {
#pragma unroll
                for (int j = 0; j < 4; ++j) {
                    int row = brow + wr * 64 + m * 16 + hi * 4 + j;
                    int col = bcol + wc * 64 + n * 16 + lo;
                    size_t idx = (size_t)row * N + col + zC;
                    float v = acc[m][n][j];
                    if (EPI == EPI_SILU) v = v / (1.f + __expf(-v));
                    if (EPI == EPI_RES)  v += Res[idx];
                    if (OUT == OUT_F32) {
                        ((float*)Cp)[idx] = v;
                    } else if (OUT == OUT_BF16) {
                        ((bf16*)Cp)[idx] = __float2bfloat16(v);
                    } else {
                        bf16 vh = __float2bfloat16(v);
                        ((bf16*)Cp)[idx] = vh;
                        Clo[idx] = __float2bfloat16(v - __bfloat162float(vh));
                    }
                }
            }
        }
    }
}

// ---- split x fp32 -> (hi, lo) bf16 pair, vectorized ----
__global__ void split_x_kernel(const float* __restrict__ x,
                               bf16* __restrict__ xh, bf16* __restrict__ xl)
{
    size_t i = ((size_t)blockIdx.x * 256 + threadIdx.x) * 4;
    float4 v = *(const float4*)(x + i);
    float vv[4] = {v.x, v.y, v.z, v.w};
    unsigned short rh[4], rl[4];
#pragma unroll
    for (int j = 0; j < 4; ++j) {
        bf16 h_ = __float2bfloat16(vv[j]);
        bf16 l_ = __float2bfloat16(vv[j] - __bfloat162float(h_));
        rh[j] = *(unsigned short*)&h_;
        rl[j] = *(unsigned short*)&l_;
    }
    ushort4 oh = {rh[0], rh[1], rh[2], rh[3]};
    ushort4 ol = {rl[0], rl[1], rl[2], rl[3]};
    *(ushort4*)(xh + i) = oh;
    *(ushort4*)(xl + i) = ol;
}

// ---- transpose + split all 10 weights in one dispatch (z = weight idx) ----
struct WPack { const float* W[10]; bf16* H[10]; bf16* L[10]; };

__global__ void transw_all_kernel(WPack p)
{
    const float* W  = p.W[blockIdx.z];
    bf16* WTh = p.H[blockIdx.z];
    bf16* WTl = p.L[blockIdx.z];
    __shared__ float tile[32][33];
    int bx = blockIdx.x * 32, by = blockIdx.y * 32;
    int tx = threadIdx.x, ty = threadIdx.y;      // (32, 8)
#pragma unroll
    for (int i = 0; i < 32; i += 8)
        tile[ty + i][tx] = W[(size_t)(by + ty + i) * 512 + bx + tx];
    __syncthreads();
#pragma unroll
    for (int i = 0; i < 32; i += 8) {
        float v = tile[tx][ty + i];
        bf16 h_ = __float2bfloat16(v);
        size_t idx = (size_t)(bx + ty + i) * 512 + by + tx;
        WTh[idx] = h_;
        if (WTl) WTl[idx] = __float2bfloat16(v - __bfloat162float(h_));
    }
}

// ---- per-column (over q) online max/sumexp partials on S[4096,4096] ----
__global__ void colstats_part_kernel(const float* __restrict__ S,
                                     float* __restrict__ mp, float* __restrict__ zp)
{
    int col = blockIdx.x * 256 + threadIdx.x;
    int r0  = blockIdx.y * 256;
    float m = -1e30f, z = 0.f;
    for (int r = 0; r < 256; ++r) {
        float s  = S[(size_t)(r0 + r) * 4096 + col];
        float nm = fmaxf(m, s);
        z = z * __expf(m - nm) + __expf(s - nm);
        m = nm;
    }
    mp[blockIdx.y * 4096 + col] = m;
    zp[blockIdx.y * 4096 + col] = z;
}

__global__ void colstats_comb_kernel(const float* __restrict__ mp, const float* __restrict__ zp,
                                     float* __restrict__ mcol, float* __restrict__ rinv)
{
    int col = blockIdx.x * 256 + threadIdx.x;
    float m = -1e30f;
#pragma unroll
    for (int i = 0; i < 16; ++i) m = fmaxf(m, mp[i * 4096 + col]);
    float z = 0.f;
#pragma unroll
    for (int i = 0; i < 16; ++i) z += zp[i * 4096 + col] * __expf(mp[i * 4096 + col] - m);
    mcol[col] = m;
    rinv[col] = 1.f / z;
}

// ---- P[q,k] = bf16( exp(S[q,k] - mcol[k]) * rinv[k] ) ----
__global__ void exp_p_kernel(const float* __restrict__ S, const float* __restrict__ mcol,
                             const float* __restrict__ rinv, bf16* __restrict__ P)
{
    size_t i = ((size_t)blockIdx.x * 256 + threadIdx.x) * 4;
    int k = (int)(i & 4095);
    float4 s  = *(const float4*)(S + i);
    float4 mc = *(const float4*)(mcol + k);
    float4 rv = *(const float4*)(rinv + k);
    bf16 b0 = __float2bfloat16(__expf(s.x - mc.x) * rv.x);
    bf16 b1 = __float2bfloat16(__expf(s.y - mc.y) * rv.y);
    bf16 b2 = __float2bfloat16(__expf(s.z - mc.z) * rv.z);
    bf16 b3 = __float2bfloat16(__expf(s.w - mc.w) * rv.w);
    ushort4 o;
    o.x = *(unsigned short*)&b0; o.y = *(unsigned short*)&b1;
    o.z = *(unsigned short*)&b2; o.w = *(unsigned short*)&b3;
    *(ushort4*)(P + i) = o;
}

// ---------------------------------------------------------------------------
extern "C" void kernel_launch(void* const* d_in, const int* in_sizes, int n_in,
                              void* d_out, int out_size, void* d_ws, size_t ws_size,
                              hipStream_t stream)
{
    const int B = 4, N = 4096, D = 512;
    const size_t MALL = (size_t)B * N;          // 16384
    const size_t ND = MALL * D;                 // 8.4M elems
    const size_t NN = (size_t)N * N;            // 16.7M elems
    const float* x = (const float*)d_in[0];
    const float* Wf[10];
    for (int i = 0; i < 10; ++i) Wf[i] = (const float*)d_in[1 + i];
    // Wf: 0 qW1, 1 qW2, 2 kW1, 3 kW2, 4 vW1, 5 vW2, 6 aWq, 7 aWk, 8 aWv, 9 Wout

    char* ws = (char*)d_ws;
    size_t off = 0;
    auto carve = [&](size_t bytes) -> char* {
        char* p = ws + off;
        off = (off + bytes + 255) & ~(size_t)255;
        return p;
    };

    // Regions A..D are consecutive 32-MiB carves -> after they die they form
    // P_all[4] at uniform element stride NN for the z-batched PV GEMM.
    const size_t PBYTES = NN * 2;                               // 32 MiB
    bf16* xh  = (bf16*)carve(PBYTES);   bf16* xl  = xh  + ND;   // A
    bf16* t1h = (bf16*)carve(PBYTES);   bf16* t1l = t1h + ND;   // B
    bf16* hh  = (bf16*)carve(PBYTES);   bf16* hl  = hh  + ND;   // C
    bf16* Qh  = (bf16*)carve(PBYTES);   bf16* Ql  = Qh  + ND;   // D
    bf16* Kh  = (bf16*)carve(PBYTES);   bf16* Kl  = Kh  + ND;   // E
    bf16* VT  = (bf16*)carve((size_t)B * D * N * 2);            // G, 16.8 MB
    // weights: split pairs for q/k chains + Wout; hi-only for V chain (4,5,8)
    bf16 *wH[10], *wL[10];
    for (int i = 0; i < 10; ++i) {
        bool pair = !(i == 4 || i == 5 || i == 8);
        wH[i] = (bf16*)carve((pair ? 2 : 1) * (size_t)D * D * 2);
        wL[i] = pair ? wH[i] + (size_t)D * D : nullptr;
    }
    float* mp   = (float*)carve(16 * 4096 * 4);
    float* zp   = (float*)carve(16 * 4096 * 4);
    float* mcol = (float*)carve(4096 * 4);
    float* rinv = (float*)carve(4096 * 4);
    float* S    = (float*)carve(NN * 4);                        // I, 67 MB
    bool fit = (ws_size >= off);                                // ~249 MiB
    if (!fit) S = (float*)xh;            // fallback: S in dead A+B regions
    bf16* O = Kh;                        // O[b] -> Kh plane slice b (dead then)
    (void)in_sizes; (void)n_in; (void)out_size;

    // ---- input split + all weight transposes (one dispatch) ----
    split_x_kernel<<<dim3((unsigned)(ND / 1024)), 256, 0, stream>>>(x, xh, xl);
    WPack wp;
    for (int i = 0; i < 10; ++i) { wp.W[i] = Wf[i]; wp.H[i] = wH[i]; wp.L[i] = wL[i]; }
    transw_all_kernel<<<dim3(16, 16, 10), dim3(32, 8), 0, stream>>>(wp);

    // ---- ResiMLP branches: q, k split-3 -> Q,K ; v split-0 -> VT direct ----
    dim3 gB(D / 128, (unsigned)(MALL / 128));
    // q branch
    gemm_bt<3, EPI_SILU, OUT_SPLIT><<<gB, 256, 0, stream>>>(
        xh, xl, wH[0], wL[0], t1h, t1l, nullptr, (int)MALL, D, D, 0, 0, 0);
    gemm_bt<3, EPI_RES, OUT_SPLIT><<<gB, 256, 0, stream>>>(
        t1h, t1l, wH[1], wL[1], hh, hl, x, (int)MALL, D, D, 0, 0, 0);
    gemm_bt<3, EPI_NONE, OUT_SPLIT><<<gB, 256, 0, stream>>>(
        hh, hl, wH[6], wL[6], Qh, Ql, nullptr, (int)MALL, D, D, 0, 0, 0);
    // k branch
    gemm_bt<3, EPI_SILU, OUT_SPLIT><<<gB, 256, 0, stream>>>(
        xh, xl, wH[2], wL[2], t1h, t1l, nullptr, (int)MALL, D, D, 0, 0, 0);
    gemm_bt<3, EPI_RES, OUT_SPLIT><<<gB, 256, 0, stream>>>(
        t1h, t1l, wH[3], wL[3], hh, hl, x, (int)MALL, D, D, 0, 0, 0);
    gemm_bt<3, EPI_NONE, OUT_SPLIT><<<gB, 256, 0, stream>>>(
        hh, hl, wH[7], wL[7], Kh, Kl, nullptr, (int)MALL, D, D, 0, 0, 0);
    // v branch (plain bf16; last GEMM writes VT[b][d][token] directly)
    gemm_bt<0, EPI_SILU, OUT_BF16><<<gB, 256, 0, stream>>>(
        xh, nullptr, wH[4], nullptr, t1h, nullptr, nullptr, (int)MALL, D, D, 0, 0, 0);
    gemm_bt<0, EPI_RES, OUT_BF16><<<gB, 256, 0, stream>>>(
        t1h, nullptr, wH[5], nullptr, hh, nullptr, x, (int)MALL, D, D, 0, 0, 0);
    gemm_bt<0, EPI_NONE, OUT_VT><<<gB, 256, 0, stream>>>(
        hh, nullptr, wH[8], nullptr, VT, nullptr, nullptr, (int)MALL, D, D, 0, 0, 0);

    // ---- per batch: S = QK^T (split-3); column stats; P (1/Z prescaled) ----
    bf16* P_all = xh;                    // A,B,C,D regions, stride NN
    for (int b = 0; b < B; ++b) {
        size_t boff = (size_t)b * N * D;
        gemm_bt<3, EPI_NONE, OUT_F32><<<dim3(N / 128, N / 128), 256, 0, stream>>>(
            Qh + boff, Ql + boff, Kh + boff, Kl + boff, S, nullptr, nullptr,
            N, N, D, 0, 0, 0);
        colstats_part_kernel<<<dim3(16, 16), 256, 0, stream>>>(S, mp, zp);
        colstats_comb_kernel<<<16, 256, 0, stream>>>(mp, zp, mcol, rinv);
        bf16* Pb = fit ? (P_all + (size_t)b * NN) : (bf16*)d_out;
        exp_p_kernel<<<(unsigned)(NN / 1024), 256, 0, stream>>>(S, mcol, rinv, Pb);
        if (!fit) {
            gemm_bt<0, EPI_NONE, OUT_BF16><<<dim3(D / 128, N / 128), 256, 0, stream>>>(
                Pb, nullptr, VT + (size_t)b * D * N, nullptr, O + boff,
                nullptr, nullptr, N, D, N, 0, 0, 0);
        }
    }

    // ---- z-batched PV: O[b] = P[b] @ VT[b]^T, 512 blocks ----
    if (fit) {
        gemm_bt<0, EPI_NONE, OUT_BF16><<<dim3(D / 128, N / 128, B), 256, 0, stream>>>(
            P_all, nullptr, VT, nullptr, O, nullptr, nullptr,
            N, D, N, NN, (unsigned long long)D * N, (unsigned long long)N * D);
    }

    // ---- final projection: d_out = O @ (WoutHi + WoutLo) ----
    gemm_bt<2, EPI_NONE, OUT_F32><<<gB, 256, 0, stream>>>(
        O, nullptr, wH[9], wL[9], d_out, nullptr, nullptr,
        (int)MALL, D, D, 0, 0, 0);
}

// Round 5
// 730.914 us; speedup vs baseline: 1.6386x; 1.1326x over previous
//
#include <hip/hip_runtime.h>
#include <hip/hip_bf16.h>
#include <stdint.h>
#include <stddef.h>

typedef __hip_bfloat16 bf16;
typedef __attribute__((ext_vector_type(8))) short short8;
typedef __attribute__((ext_vector_type(4))) float f32x4;

#define EPI_NONE 0
#define EPI_SILU 1
#define EPI_RES  2
#define OUT_BF16  0
#define OUT_F32   1
#define OUT_SPLIT 2
#define OUT_VT    3   // write C transposed into VT[b][d][token], token = row
#define OUT_STATS 4   // f32 C + fused per-column (over rows) max/sumexp partials

__device__ __forceinline__ void gll16(const bf16* g, char* l) {
    __builtin_amdgcn_global_load_lds(
        (const __attribute__((address_space(1))) void*)g,
        (__attribute__((address_space(3))) void*)l, 16, 0, 0);
}

// ---------------------------------------------------------------------------
// m97-structure bf16 GEMM, bf16x3 split inputs optional, z-batching, lda/ldb/
// ldc leading dims, XCD-aware block swizzle (bijective; all grids %8==0),
// LDS XOR-swizzle (0 bank conflicts, verified r3), fused column-stats epilogue.
// ---------------------------------------------------------------------------
template<int SPLIT, int EPI, int OUT>
__global__ __launch_bounds__(256)
void gemm_bt(const bf16* __restrict__ Ahi, const bf16* __restrict__ Alo,
             const bf16* __restrict__ Bhi, const bf16* __restrict__ Blo,
             void* __restrict__ Cp, bf16* __restrict__ Clo,
             const float* __restrict__ Res,
             float* __restrict__ mp, float* __restrict__ zp,
             int M, int N, int K, int lda, int ldb, int ldc, int ldr,
             unsigned long long sA, unsigned long long sB, unsigned long long sC)
{
    constexpr bool SA = (SPLIT & 1) != 0;
    constexpr bool SB = (SPLIT & 2) != 0;

    const size_t zA = (size_t)blockIdx.z * sA;
    const size_t zB = (size_t)blockIdx.z * sB;
    const size_t zC = (size_t)blockIdx.z * sC;
    Ahi += zA; Bhi += zB;
    if constexpr (SA) Alo += zA;
    if constexpr (SB) Blo += zB;

    // ---- XCD-aware bijective swizzle on the (x,y) plane (nwg % 8 == 0) ----
    unsigned nwg = gridDim.x * gridDim.y;
    unsigned lin = blockIdx.y * gridDim.x + blockIdx.x;
    unsigned cpx = nwg >> 3;
    unsigned swz = (lin & 7) * cpx + (lin >> 3);
    unsigned bxs = swz % gridDim.x, bys = swz / gridDim.x;

    const int t    = threadIdx.x;
    const int w    = t >> 6;
    const int lane = t & 63;
    const int wr   = w >> 1, wc = w & 1;
    const int lo   = lane & 15, hi = lane >> 4;
    const int brow = bys * 128;
    const int bcol = bxs * 128;

    __shared__ bf16 AsH[128 * 64];
    __shared__ bf16 BsH[128 * 64];
    __shared__ bf16 AsL[SA ? 128 * 64 : 8];
    __shared__ bf16 BsL[SB ? 128 * 64 : 8];
    __shared__ float smst[(OUT == OUT_STATS) ? 512 : 4];

    f32x4 acc[4][4];
#pragma unroll
    for (int m = 0; m < 4; ++m)
#pragma unroll
        for (int n = 0; n < 4; ++n)
            acc[m][n] = (f32x4){0.f, 0.f, 0.f, 0.f};

    const int r0 = t >> 3;                             // row in 32-row stripe
    const int cswz = ((t & 7) ^ ((t >> 3) & 7)) * 8;   // inverse-swizzled src
    const int rA7  = lo & 7;                           // read-side row parity

    for (int k0 = 0; k0 < K; k0 += 64) {
#pragma unroll
        for (int i = 0; i < 4; ++i) {
            int r = i * 32 + r0;
            size_t aoff = (size_t)(brow + r) * lda + (k0 + cswz);
            size_t boff = (size_t)(bcol + r) * ldb + (k0 + cswz);
            int ldst = i * 4096 + w * 1024;            // wave-uniform LDS base
            gll16(Ahi + aoff, (char*)AsH + ldst);
            gll16(Bhi + boff, (char*)BsH + ldst);
            if constexpr (SA) gll16(Alo + aoff, (char*)AsL + ldst);
            if constexpr (SB) gll16(Blo + boff, (char*)BsL + ldst);
        }
        __syncthreads();

#pragma unroll
        for (int kk = 0; kk < 64; kk += 32) {
            short8 aH[4], bH[4], aL[4], bL[4];
#pragma unroll
            for (int m = 0; m < 4; ++m) {
                int idx = (wr * 64 + m * 16 + lo) * 64 +
                          ((((kk >> 3) + hi) ^ rA7) * 8);
                aH[m] = *(const short8*)&AsH[idx];
                if constexpr (SA) aL[m] = *(const short8*)&AsL[idx];
            }
#pragma unroll
            for (int n = 0; n < 4; ++n) {
                int idx = (wc * 64 + n * 16 + lo) * 64 +
                          ((((kk >> 3) + hi) ^ rA7) * 8);
                bH[n] = *(const short8*)&BsH[idx];
                if constexpr (SB) bL[n] = *(const short8*)&BsL[idx];
            }
#pragma unroll
            for (int m = 0; m < 4; ++m)
#pragma unroll
                for (int n = 0; n < 4; ++n) {
                    acc[m][n] = __builtin_amdgcn_mfma_f32_16x16x32_bf16(
                        aH[m], bH[n], acc[m][n], 0, 0, 0);
                    if constexpr (SB)
                        acc[m][n] = __builtin_amdgcn_mfma_f32_16x16x32_bf16(
                            aH[m], bL[n], acc[m][n], 0, 0, 0);
                    if constexpr (SA)
                        acc[m][n] = __builtin_amdgcn_mfma_f32_16x16x32_bf16(
                            aL[m], bH[n], acc[m][n], 0, 0, 0);
                }
        }
        __syncthreads();
    }

    // ---- epilogue: C writes ----
#pragma unroll
    for (int m = 0; m < 4; ++m) {
#pragma unroll
        for (int n = 0; n < 4; ++n) {
            if constexpr (OUT == OUT_VT) {
                int row0 = brow + wr * 64 + m * 16 + hi * 4;
                int col  = bcol + wc * 64 + n * 16 + lo;      // d index
                int bb = row0 >> 12, n0 = row0 & 4095;
                unsigned short u[4];
#pragma unroll
                for (int j = 0; j < 4; ++j) {
                    bf16 vb = __float2bfloat16(acc[m][n][j]);
                    u[j] = *(unsigned short*)&vb;
                }
                ushort4 pack = {u[0], u[1], u[2], u[3]};
                *(ushort4*)&((bf16*)Cp)[((size_t)(bb * 512 + col) << 12) + n0] = pack;
            } else {
#pragma unroll
                for (int j = 0; j < 4; ++j) {
                    int row = brow + wr * 64 + m * 16 + hi * 4 + j;
                    int col = bcol + wc * 64 + n * 16 + lo;
                    size_t idx = (size_t)row * ldc + col + zC;
                    float v = acc[m][n][j];
                    if (EPI == EPI_SILU) v = v / (1.f + __expf(-v));
                    if (EPI == EPI_RES)  v += Res[(size_t)row * ldr + col];
                    if (OUT == OUT_F32 || OUT == OUT_STATS) {
                        ((float*)Cp)[idx] = v;
                    } else if (OUT == OUT_BF16) {
                        ((bf16*)Cp)[idx] = __float2bfloat16(v);
                    } else if (OUT == OUT_SPLIT) {
                        bf16 vh = __float2bfloat16(v);
                        ((bf16*)Cp)[idx] = vh;
                        Clo[idx] = __float2bfloat16(v - __bfloat162float(vh));
                    }
                }
            }
        }
    }

    // ---- fused per-column (over the block's 128 rows) max/sumexp ----
    if constexpr (OUT == OUT_STATS) {
#pragma unroll
        for (int n = 0; n < 4; ++n) {
            float ml = acc[0][n][0];
#pragma unroll
            for (int m = 0; m < 4; ++m)
#pragma unroll
                for (int j = 0; j < 4; ++j) ml = fmaxf(ml, acc[m][n][j]);
            float zl = 0.f;
#pragma unroll
            for (int m = 0; m < 4; ++m)
#pragma unroll
                for (int j = 0; j < 4; ++j) zl += __expf(acc[m][n][j] - ml);
            // reduce across hi lanes (lane bits 4,5): 16 -> 64 rows
#pragma unroll
            for (int d = 16; d <= 32; d <<= 1) {
                float mo = __shfl_xor(ml, d);
                float zo = __shfl_xor(zl, d);
                float nm = fmaxf(ml, mo);
                zl = zl * __expf(ml - nm) + zo * __expf(mo - nm);
                ml = nm;
            }
            if (hi == 0) {
                int c = wc * 64 + n * 16 + lo;
                smst[wr * 256 + c]       = ml;
                smst[wr * 256 + 128 + c] = zl;
            }
        }
        __syncthreads();
        if (t < 128) {                        // combine the two wr halves
            float m0 = smst[t],       z0 = smst[128 + t];
            float m1 = smst[256 + t], z1 = smst[384 + t];
            float nm = fmaxf(m0, m1);
            float zz = z0 * __expf(m0 - nm) + z1 * __expf(m1 - nm);
            size_t o = (size_t)(brow >> 7) * 4096 + bcol + t;
            mp[o] = nm;
            zp[o] = zz;
        }
    }
}

// ---- split x fp32 -> (hi, lo) bf16 pair, vectorized ----
__global__ void split_x_kernel(const float* __restrict__ x,
                               bf16* __restrict__ xh, bf16* __restrict__ xl)
{
    size_t i = ((size_t)blockIdx.x * 256 + threadIdx.x) * 4;
    float4 v = *(const float4*)(x + i);
    float vv[4] = {v.x, v.y, v.z, v.w};
    unsigned short rh[4], rl[4];
#pragma unroll
    for (int j = 0; j < 4; ++j) {
        bf16 h_ = __float2bfloat16(vv[j]);
        bf16 l_ = __float2bfloat16(vv[j] - __bfloat162float(h_));
        rh[j] = *(unsigned short*)&h_;
        rl[j] = *(unsigned short*)&l_;
    }
    ushort4 oh = {rh[0], rh[1], rh[2], rh[3]};
    ushort4 ol = {rl[0], rl[1], rl[2], rl[3]};
    *(ushort4*)(xh + i) = oh;
    *(ushort4*)(xl + i) = ol;
}

// ---- transpose + split all 10 weights in one dispatch (z = weight idx) ----
struct WPack { const float* W[10]; bf16* H[10]; bf16* L[10]; };

__global__ void transw_all_kernel(WPack p)
{
    const float* W  = p.W[blockIdx.z];
    bf16* WTh = p.H[blockIdx.z];
    bf16* WTl = p.L[blockIdx.z];
    __shared__ float tile[32][33];
    int bx = blockIdx.x * 32, by = blockIdx.y * 32;
    int tx = threadIdx.x, ty = threadIdx.y;      // (32, 8)
#pragma unroll
    for (int i = 0; i < 32; i += 8)
        tile[ty + i][tx] = W[(size_t)(by + ty + i) * 512 + bx + tx];
    __syncthreads();
#pragma unroll
    for (int i = 0; i < 32; i += 8) {
        float v = tile[tx][ty + i];
        bf16 h_ = __float2bfloat16(v);
        size_t idx = (size_t)(bx + ty + i) * 512 + by + tx;
        WTh[idx] = h_;
        if (WTl) WTl[idx] = __float2bfloat16(v - __bfloat162float(h_));
    }
}

// ---- combine 32 row-block partials -> mcol, rinv ----
__global__ void colstats_comb_kernel(const float* __restrict__ mp, const float* __restrict__ zp,
                                     float* __restrict__ mcol, float* __restrict__ rinv)
{
    int col = blockIdx.x * 256 + threadIdx.x;
    float m = -1e30f;
#pragma unroll
    for (int i = 0; i < 32; ++i) m = fmaxf(m, mp[i * 4096 + col]);
    float z = 0.f;
#pragma unroll
    for (int i = 0; i < 32; ++i) z += zp[i * 4096 + col] * __expf(mp[i * 4096 + col] - m);
    mcol[col] = m;
    rinv[col] = 1.f / z;
}

// ---- P[q,k] = bf16( exp(S[q,k] - mcol[k]) * rinv[k] ) ----
__global__ void exp_p_kernel(const float* __restrict__ S, const float* __restrict__ mcol,
                             const float* __restrict__ rinv, bf16* __restrict__ P)
{
    size_t i = ((size_t)blockIdx.x * 256 + threadIdx.x) * 4;
    int k = (int)(i & 4095);
    float4 s  = *(const float4*)(S + i);
    float4 mc = *(const float4*)(mcol + k);
    float4 rv = *(const float4*)(rinv + k);
    bf16 b0 = __float2bfloat16(__expf(s.x - mc.x) * rv.x);
    bf16 b1 = __float2bfloat16(__expf(s.y - mc.y) * rv.y);
    bf16 b2 = __float2bfloat16(__expf(s.z - mc.z) * rv.z);
    bf16 b3 = __float2bfloat16(__expf(s.w - mc.w) * rv.w);
    ushort4 o;
    o.x = *(unsigned short*)&b0; o.y = *(unsigned short*)&b1;
    o.z = *(unsigned short*)&b2; o.w = *(unsigned short*)&b3;
    *(ushort4*)(P + i) = o;
}

// ---------------------------------------------------------------------------
extern "C" void kernel_launch(void* const* d_in, const int* in_sizes, int n_in,
                              void* d_out, int out_size, void* d_ws, size_t ws_size,
                              hipStream_t stream)
{
    const int B = 4, N = 4096, D = 512;
    const size_t MALL = (size_t)B * N;          // 16384
    const size_t ND = MALL * D;                 // 8.4M elems
    const size_t NN = (size_t)N * N;            // 16.7M elems
    const size_t WW = (size_t)D * D;            // 262144
    const float* x = (const float*)d_in[0];
    const float* Wf[10];
    for (int i = 0; i < 10; ++i) Wf[i] = (const float*)d_in[1 + i];
    // Wf: 0 qW1, 1 qW2, 2 kW1, 3 kW2, 4 vW1, 5 vW2, 6 aWq, 7 aWk, 8 aWv, 9 Wout

    char* ws = (char*)d_ws;
    size_t off = 0;
    auto carve = [&](size_t bytes) -> char* {
        char* p = ws + off;
        off = (off + bytes + 255) & ~(size_t)255;
        return p;
    };

    // 5 consecutive 32-MiB planes. Lifetimes:
    //   A: x split            -> P[0]
    //   B: (t1v) then hh      -> P[1]
    //   C: (hv)  then hl      -> P[2]
    //   D: t1h   then QKh     -> P[3]   (written after last QK^T)
    //   E: t1l   then QKl     -> O      (PV output)
    // P_all = plane A with uniform stride NN elems (= exactly one plane).
    const size_t PLANE = NN * 2;                 // 33,554,432 B
    bf16* xh  = (bf16*)carve(PLANE);  bf16* xl  = xh + ND;     // A
    bf16* hh  = (bf16*)carve(PLANE);                           // B (t1v first)
    bf16* hl  = (bf16*)carve(PLANE);                           // C (hv first)
    bf16* t1h = (bf16*)carve(PLANE);                           // D -> QKh
    bf16* t1l = (bf16*)carve(PLANE);                           // E -> QKl
    float* S  = (float*)carve(NN * 4);                         // 64 MiB
    bf16* VT  = (bf16*)carve((size_t)B * D * N * 2);           // 16 MiB
    // weights: concat pairs for q/k (W1,W2,aW), singles for v, pair for Wout
    bf16* wc1H = (bf16*)carve(2 * WW * 2);  bf16* wc1L = (bf16*)carve(2 * WW * 2);
    bf16* wc2H = (bf16*)carve(2 * WW * 2);  bf16* wc2L = (bf16*)carve(2 * WW * 2);
    bf16* wcAH = (bf16*)carve(2 * WW * 2);  bf16* wcAL = (bf16*)carve(2 * WW * 2);
    bf16* wv1H = (bf16*)carve(WW * 2);
    bf16* wv2H = (bf16*)carve(WW * 2);
    bf16* wv3H = (bf16*)carve(WW * 2);
    bf16* woH  = (bf16*)carve(WW * 2);      bf16* woL  = (bf16*)carve(WW * 2);
    float* mp   = (float*)carve(32 * 4096 * 4);
    float* zp   = (float*)carve(32 * 4096 * 4);
    float* mcol = (float*)carve(4096 * 4);
    float* rinv = (float*)carve(4096 * 4);
    // total = 261,652,480 B <= 262,701,056 proven writable in round 2.
    bf16* t1v = hh;          // v-branch scratch (before h is written)
    bf16* hv  = hl;
    bf16* QKh = t1h;         // [16384][1024]: cols 0-511 = Q, 512-1023 = K
    bf16* QKl = t1l;
    bf16* P_all = xh;        // planes A..D, stride NN
    bf16* O   = t1l;         // plane E after QK dead
    (void)in_sizes; (void)n_in; (void)out_size; (void)ws_size;

    // ---- input split + all weight transposes ----
    split_x_kernel<<<dim3((unsigned)(ND / 1024)), 256, 0, stream>>>(x, xh, xl);
    WPack wp;
    wp.W[0] = Wf[0]; wp.H[0] = wc1H;      wp.L[0] = wc1L;        // qW1
    wp.W[1] = Wf[2]; wp.H[1] = wc1H + WW; wp.L[1] = wc1L + WW;   // kW1
    wp.W[2] = Wf[1]; wp.H[2] = wc2H;      wp.L[2] = wc2L;        // qW2
    wp.W[3] = Wf[3]; wp.H[3] = wc2H + WW; wp.L[3] = wc2L + WW;   // kW2
    wp.W[4] = Wf[6]; wp.H[4] = wcAH;      wp.L[4] = wcAL;        // aWq
    wp.W[5] = Wf[7]; wp.H[5] = wcAH + WW; wp.L[5] = wcAL + WW;   // aWk
    wp.W[6] = Wf[4]; wp.H[6] = wv1H;      wp.L[6] = nullptr;     // vW1
    wp.W[7] = Wf[5]; wp.H[7] = wv2H;      wp.L[7] = nullptr;     // vW2
    wp.W[8] = Wf[8]; wp.H[8] = wv3H;      wp.L[8] = nullptr;     // aWv
    wp.W[9] = Wf[9]; wp.H[9] = woH;       wp.L[9] = woL;         // Wout
    transw_all_kernel<<<dim3(16, 16, 10), dim3(32, 8), 0, stream>>>(wp);

    const int M16 = (int)MALL;
    // ---- v branch first (plain bf16; scratch in planes B,C; VT direct) ----
    gemm_bt<0, EPI_SILU, OUT_BF16><<<dim3(4, 128), 256, 0, stream>>>(
        xh, nullptr, wv1H, nullptr, t1v, nullptr, nullptr, nullptr, nullptr,
        M16, 512, 512, 512, 512, 512, 512, 0, 0, 0);
    gemm_bt<0, EPI_RES, OUT_BF16><<<dim3(4, 128), 256, 0, stream>>>(
        t1v, nullptr, wv2H, nullptr, hv, nullptr, x, nullptr, nullptr,
        M16, 512, 512, 512, 512, 512, 512, 0, 0, 0);
    gemm_bt<0, EPI_NONE, OUT_VT><<<dim3(4, 128), 256, 0, stream>>>(
        hv, nullptr, wv3H, nullptr, VT, nullptr, nullptr, nullptr, nullptr,
        M16, 512, 512, 512, 512, 512, 512, 0, 0, 0);

    // ---- q+k branches batched (split-3): concat-N then z=2 ----
    gemm_bt<3, EPI_SILU, OUT_SPLIT><<<dim3(8, 128), 256, 0, stream>>>(
        xh, xl, wc1H, wc1L, t1h, t1l, nullptr, nullptr, nullptr,
        M16, 1024, 512, 512, 512, 1024, 512, 0, 0, 0);
    gemm_bt<3, EPI_RES, OUT_SPLIT><<<dim3(4, 128, 2), 256, 0, stream>>>(
        t1h, t1l, wc2H, wc2L, hh, hl, x, nullptr, nullptr,
        M16, 512, 512, 1024, 512, 1024, 512, 512, WW, 512);
    gemm_bt<3, EPI_NONE, OUT_SPLIT><<<dim3(4, 128, 2), 256, 0, stream>>>(
        hh, hl, wcAH, wcAL, QKh, QKl, nullptr, nullptr, nullptr,
        M16, 512, 512, 1024, 512, 1024, 512, 512, WW, 512);

    // ---- per batch: S = QK^T (split-3, fused col-stats); comb; P ----
    for (int b = 0; b < B; ++b) {
        size_t boff = (size_t)b * N * 1024;
        gemm_bt<3, EPI_NONE, OUT_STATS><<<dim3(32, 32), 256, 0, stream>>>(
            QKh + boff, QKl + boff, QKh + boff + 512, QKl + boff + 512,
            S, nullptr, nullptr, mp, zp,
            N, N, 512, 1024, 1024, 4096, 4096, 0, 0, 0);
        colstats_comb_kernel<<<16, 256, 0, stream>>>(mp, zp, mcol, rinv);
        exp_p_kernel<<<(unsigned)(NN / 1024), 256, 0, stream>>>(
            S, mcol, rinv, P_all + (size_t)b * NN);
    }

    // ---- z-batched PV: O[b] = P[b] @ VT[b]^T ----
    gemm_bt<0, EPI_NONE, OUT_BF16><<<dim3(4, 32, 4), 256, 0, stream>>>(
        P_all, nullptr, VT, nullptr, O, nullptr, nullptr, nullptr, nullptr,
        N, 512, N, 4096, 4096, 512, 512,
        NN, (unsigned long long)D * N, (unsigned long long)N * D);

    // ---- final projection: d_out = O @ (WoutHi + WoutLo) ----
    gemm_bt<2, EPI_NONE, OUT_F32><<<dim3(4, 128), 256, 0, stream>>>(
        O, nullptr, woH, woL, d_out, nullptr, nullptr, nullptr, nullptr,
        M16, 512, 512, 512, 512, 512, 512, 0, 0, 0);
}